// Round 2
// baseline (639.563 us; speedup 1.0000x reference)
//
#include <hip/hip_runtime.h>

// Problem constants (from reference setup_inputs)
#define T_STEPS 15
#define CIN     64
#define H_IN    256
#define W_IN    256
#define COUT    128
#define HO      252
#define WO      252
#define KWIN    16
#define KH      5
#define KW      5
#define LOWERB  0.0f
#define UPPERB  1.0f

#define CKK     (CIN * KH * KW)          // 1600 (divisible by 4)
#define W_ELEMS (COUT * CKK)             // 204800
#define NVEC    (W_ELEMS / 4)            // 51200 float4 groups

__global__ __launch_bounds__(256) void stdp_update_v2(
    const float* __restrict__ in_spikes,   // (T, Cin, H, W)
    const float* __restrict__ out_spikes,  // (T, Cout, Ho, Wo)
    const int*   __restrict__ winners,     // (K, 3) int32: f, r, c
    const float* __restrict__ weight,      // (Cout, Cin, KH, KW)
    const float* __restrict__ ltp,         // (Cout,)
    const float* __restrict__ ltd,         // (Cout,)
    float*       __restrict__ out)         // (Cout, Cin, KH, KW)
{
    const int g = blockIdx.x * blockDim.x + threadIdx.x;  // [0, NVEC)
    if (g >= NVEC) return;
    const int idx  = g * 4;
    const int cout = idx / CKK;            // all 4 components share cout

    // Winner table: constant indices -> wave-uniform -> scalar loads.
    // Search + select via cndmask (no dynamic register-array indexing).
    bool win = false;
    int  wr = 0, wc = 0;
    #pragma unroll
    for (int i = 0; i < KWIN; ++i) {
        const int f = winners[3 * i + 0];
        const int r = winners[3 * i + 1];
        const int c = winners[3 * i + 2];
        if (f == cout) { win = true; wr = r; wc = c; }
    }

    float4 w = ((const float4*)weight)[g];
    float* pw = (float*)&w;

    if (win) {
        // out_lat[cout, wr, wc]: 15 loads, shared by all threads of this cout
        // (L2/L1 broadcast; only 240 distinct addresses chip-wide).
        float ol = 0.0f;
        const size_t ob = (size_t)cout * (HO * WO) + (size_t)wr * WO + (size_t)wc;
        #pragma unroll
        for (int t = 0; t < T_STEPS; ++t)
            ol += out_spikes[ob + (size_t)t * (COUT * HO * WO)];

        const float ltpv = ltp[cout];
        const float ltdv = ltd[cout];

        #pragma unroll
        for (int j = 0; j < 4; ++j) {
            const int rem = idx + j - cout * CKK;
            const int cin = rem / (KH * KW);
            const int p   = rem % (KH * KW);
            const int kh  = p / KW;
            const int kw  = p % KW;
            // in_lat[cin, wr+kh, wc+kw]; wr<=251, kh<=4 -> row <= 255 in bounds
            const size_t ib = (size_t)cin * (H_IN * W_IN)
                            + (size_t)(wr + kh) * W_IN + (size_t)(wc + kw);
            float s = 0.0f;
            #pragma unroll
            for (int t = 0; t < T_STEPS; ++t)
                s += in_spikes[ib + (size_t)t * (CIN * H_IN * W_IN)];
            const float lr = (s >= ol) ? ltpv : ltdv;
            const float v  = pw[j];
            pw[j] = v + lr * ((v - LOWERB) * (UPPERB - v));
        }
    }

    #pragma unroll
    for (int j = 0; j < 4; ++j)
        pw[j] = fminf(fmaxf(pw[j], LOWERB), UPPERB);

    ((float4*)out)[g] = w;
}

extern "C" void kernel_launch(void* const* d_in, const int* in_sizes, int n_in,
                              void* d_out, int out_size, void* d_ws, size_t ws_size,
                              hipStream_t stream) {
    const float* in_spikes  = (const float*)d_in[0];
    const float* out_spikes = (const float*)d_in[1];
    const int*   winners    = (const int*)d_in[2];
    const float* weight     = (const float*)d_in[3];
    const float* ltp        = (const float*)d_in[4];
    const float* ltd        = (const float*)d_in[5];
    float*       out        = (float*)d_out;

    const int block = 256;
    const int grid  = (NVEC + block - 1) / block;  // 200 blocks
    stdp_update_v2<<<grid, block, 0, stream>>>(
        in_spikes, out_spikes, winners, weight, ltp, ltd, out);
}